// Round 8
// baseline (319.946 us; speedup 1.0000x reference)
//
#include <hip/hip_runtime.h>

typedef __attribute__((ext_vector_type(8))) short bhalf8;
typedef __attribute__((ext_vector_type(4))) short bhalf4;
typedef __attribute__((ext_vector_type(4))) float f32x4;

__device__ __forceinline__ ushort f2bf(float f) {
  unsigned u = __builtin_bit_cast(unsigned, f);
  unsigned r = u + 0x7fffu + ((u >> 16) & 1u);
  return (ushort)(r >> 16);
}

// async global->LDS, 16B per lane. Dest = wave-uniform base + lane*16.
__device__ __forceinline__ void gld16(const ushort* g, ushort* l) {
  __builtin_amdgcn_global_load_lds((const __attribute__((address_space(1))) void*)g,
                                   (__attribute__((address_space(3))) void*)l, 16, 0, 0);
}

// ---------------- prep: converts, transposes, mask bitpack (inverted), cvec -
__global__ __launch_bounds__(256) void prep_kernel(
    const float* __restrict__ q, const int* __restrict__ mask,
    const float* __restrict__ eps1, const float* __restrict__ U_w,
    const float* __restrict__ V_w, const float* __restrict__ Wq,
    const float* __restrict__ Wk, const float* __restrict__ Wv,
    const float* __restrict__ Wo, const float* __restrict__ U_b,
    const float* __restrict__ V_b,
    ushort* __restrict__ qb, unsigned long long* __restrict__ minv,
    ushort* __restrict__ uwb, ushort* __restrict__ vwb,
    ushort* __restrict__ e1b, ushort* __restrict__ e1t,
    ushort* __restrict__ wqkv, ushort* __restrict__ wot,
    float* __restrict__ cvec) {
  int i = blockIdx.x * 256 + threadIdx.x;
  if (i < 4194304) {
    qb[i] = f2bf(q[i]);
  } else if (i < 12582912) {
    int j = i - 4194304;  // (b,qq,g) flat
    unsigned long long bb = __ballot(mask[j] != 0);
    if ((threadIdx.x & 63) == 0) {
      int b = j >> 20, qq = (j >> 10) & 1023, g = j & 1023;
      // minv[b][g>>6][q]: bit (g&63) == 1 means KEEP (mask==0)
      minv[((size_t)b * 16 + (g >> 6)) * 1024 + qq] = ~bb;
    }
  } else if (i < 13369344) {
    int j = i - 12582912;
    uwb[j] = f2bf(U_w[j]);
  } else if (i < 14155776) {
    int j = i - 13369344;
    vwb[j] = f2bf(V_w[j]);
  } else if (i < 14417920) {
    int j = i - 14155776;
    e1b[j] = f2bf(eps1[j]);
  } else if (i < 14680064) {
    int j = i - 14417920; int n = j >> 9, k = j & 511;
    e1t[j] = f2bf(eps1[k * 512 + n]);
  } else if (i < 15466496) {
    int j = i - 14680064; int n = j >> 9, d = j & 511;
    const float* W = (n < 512) ? Wq : (n < 1024 ? Wk : Wv);
    float sc = (n < 512) ? 0.02255252509f : 1.0f;  // (1/64)*log2(e) into Wq
    int nl = n & 511;
    wqkv[j] = f2bf(W[((nl >> 6) * 512 + d) * 64 + (nl & 63)] * sc);
  } else if (i < 15728640) {
    int j = i - 15466496; int d = j >> 9, hv = j & 511;
    wot[j] = f2bf(Wo[hv * 512 + d]);
  } else {
    int j = i - 15728640;  // cvec: 98304 threads = 1536 waves
    int idx = j >> 6, ln = j & 63;
    int l = idx >> 9;
    const float* vr = V_w + (size_t)idx * 512 + ln * 8;
    const float* ur = U_b + l * 512 + ln * 8;
    float s = 0;
#pragma unroll
    for (int t = 0; t < 8; t++) s += vr[t] * ur[t];
#pragma unroll
    for (int off = 1; off < 64; off <<= 1) s += __shfl_xor(s, off, 64);
    if (ln == 0) cvec[idx] = s + V_b[idx];
  }
}

// ---------------- bf16 MFMA GEMM, NT, BK=32, pipelined gld16 ----------------
// C[M,N]=A[M,K]*Bt[N,K]^T, tile 128 x BN, 256 thr, grid(x=m-blocks,y=n-blocks)
// (same-x blocks share an XCD -> A L2 reuse). Output region reg=n0>>9 with
// per-region code: 0=bf16 row-major, 1=fp32 row-major (ptr cast), 2=MFMA-tile
// scatter T[bh][t/16][d/32][t%16][d%32], 3=V^T tile scatter T[bh][g/16][v][g%16].
template <int BN>
__global__ __launch_bounds__(256) void gemm_nt(
    const ushort* __restrict__ A0, const ushort* __restrict__ A1,
    const ushort* __restrict__ Bt0, const ushort* __restrict__ Bt1,
    int bsplit, int mstride, int M, int K,
    ushort* __restrict__ Oa, const float* __restrict__ ba, int ca,
    ushort* __restrict__ Ob, const float* __restrict__ bb2, int cb,
    ushort* __restrict__ Oc, const float* __restrict__ bc, int cc) {
  __shared__ ushort As[128 * 32];
  __shared__ ushort Bs[BN * 32];
  int tid = threadIdx.x;
  int wave = tid >> 6, lane = tid & 63;
  int quad = lane >> 4, col = lane & 15;
  int m0 = blockIdx.x * 128, n0 = blockIdx.y * BN;
  const ushort* A = (A1 && n0 >= 512) ? A1 : A0;
  const ushort* Bp = ((n0 < bsplit) ? Bt0 + (size_t)n0 * K
                                    : Bt1 + (size_t)(n0 - bsplit) * K) +
                     (size_t)(m0 >> 9) * mstride;
  constexpr int NI = BN / 32;
  int wm = (BN == 128) ? (wave >> 1) * 64 : (wave & 1) * 64;
  int wn = (BN == 128) ? (wave & 1) * 64 : (wave >> 1) * 32;
  f32x4 acc[4][NI] = {};
  int srow = wave * 16 + (lane >> 2);
  int skc = (lane & 3) * 8;
  const ushort* gA0 = A + (size_t)(m0 + srow) * K + skc;
  const ushort* gA1 = gA0 + (size_t)64 * K;
  const ushort* gB0 = Bp + (size_t)srow * K + skc;
  const ushort* gB1 = gB0 + (size_t)64 * K;
  ushort* lA0 = &As[wave * 16 * 32];
  ushort* lA1 = &As[(64 + wave * 16) * 32];
  ushort* lB0 = &Bs[wave * 16 * 32];
  ushort* lB1 = (BN == 128) ? &Bs[(64 + wave * 16) * 32] : nullptr;

  gld16(gA0, lA0);
  gld16(gA1, lA1);
  gld16(gB0, lB0);
  if (BN == 128) gld16(gB1, lB1);

  for (int k0 = 0; k0 < K; k0 += 32) {
    __syncthreads();  // vmcnt drained: tile staged; prev readers done
    bhalf8 af[4], bg[NI];
#pragma unroll
    for (int i = 0; i < 4; i++)
      af[i] = *(bhalf8*)&As[(wm + i * 16 + col) * 32 + quad * 8];
#pragma unroll
    for (int i = 0; i < NI; i++)
      bg[i] = *(bhalf8*)&Bs[(wn + i * 16 + col) * 32 + quad * 8];
    __syncthreads();  // frags in regs; LDS free to overwrite
    if (k0 + 32 < K) {  // stage next tile; DMA overlaps MFMA below
      gld16(gA0 + k0 + 32, lA0);
      gld16(gA1 + k0 + 32, lA1);
      gld16(gB0 + k0 + 32, lB0);
      if (BN == 128) gld16(gB1 + k0 + 32, lB1);
    }
#pragma unroll
    for (int mi = 0; mi < 4; mi++)
#pragma unroll
      for (int ni = 0; ni < NI; ni++)
        acc[mi][ni] = __builtin_amdgcn_mfma_f32_16x16x32_bf16(af[mi], bg[ni], acc[mi][ni], 0, 0, 0);
  }

  int reg = n0 >> 9;
  ushort* O = (reg == 0) ? Oa : (reg == 1 ? Ob : Oc);
  const float* bs = (reg == 0) ? ba : (reg == 1 ? bb2 : bc);
  int code = (reg == 0) ? ca : (reg == 1 ? cb : cc);
#pragma unroll
  for (int mi = 0; mi < 4; mi++)
#pragma unroll
    for (int ni = 0; ni < NI; ni++) {
      int cn = n0 + wn + ni * 16 + col;
      int cnl = cn & 511;
      int cmb = m0 + wm + mi * 16 + quad * 4;
      float bv = bs ? bs[cnl] : 0.f;
      if (code == 2) {
        int bhh = (cmb >> 10) * 8 + (cnl >> 6);
        size_t base = ((size_t)bhh * 64 + ((cmb & 1023) >> 4)) * 1024 +
                      (size_t)((cnl >> 5) & 1) * 512 + (size_t)(cmb & 15) * 32 + (cnl & 31);
#pragma unroll
        for (int r = 0; r < 4; r++)
          O[base + r * 32] = f2bf(acc[mi][ni][r] + bv);
      } else if (code == 3) {
        int bhh = (cmb >> 10) * 8 + (cnl >> 6);
        size_t base = ((size_t)bhh * 64 + ((cmb & 1023) >> 4)) * 1024 +
                      (size_t)(cnl & 63) * 16 + (cmb & 15);
        ushort4 pk;
        pk.x = f2bf(acc[mi][ni][0] + bv);
        pk.y = f2bf(acc[mi][ni][1] + bv);
        pk.z = f2bf(acc[mi][ni][2] + bv);
        pk.w = f2bf(acc[mi][ni][3] + bv);
        *(ushort4*)&O[base] = pk;
      } else if (code == 1) {
        float* Ff = (float*)O;
#pragma unroll
        for (int r = 0; r < 4; r++)
          Ff[(size_t)(cmb + r) * 512 + cnl] = acc[mi][ni][r] + bv;
      } else {
#pragma unroll
        for (int r = 0; r < 4; r++)
          O[(size_t)(cmb + r) * 512 + cnl] = f2bf(acc[mi][ni][r] + bv);
      }
    }
}

// ---------------- fused LayerNorm + ReLU + residual (z fp32, t bf16) --------
__global__ __launch_bounds__(256) void ln_kernel(
    const float* __restrict__ z, const ushort* __restrict__ tb,
    const float* __restrict__ lgam, const float* __restrict__ lbet,
    ushort* __restrict__ hb) {
  int row = blockIdx.x * 4 + (threadIdx.x >> 6);
  int lane = threadIdx.x & 63;
  int cbase = lane * 8;
  const float* zr = z + (size_t)row * 512 + cbase;
  float x[8];
  *(float4*)&x[0] = *(const float4*)zr;
  *(float4*)&x[4] = *(const float4*)(zr + 4);
  float sum = 0;
#pragma unroll
  for (int i = 0; i < 8; i++) sum += x[i];
#pragma unroll
  for (int off = 1; off < 64; off <<= 1) sum += __shfl_xor(sum, off, 64);
  float mu = sum * (1.f / 512.f);
  float vs = 0;
#pragma unroll
  for (int i = 0; i < 8; i++) { float d = x[i] - mu; vs += d * d; }
#pragma unroll
  for (int off = 1; off < 64; off <<= 1) vs += __shfl_xor(vs, off, 64);
  float rstd = rsqrtf(vs * (1.f / 512.f) + 1e-5f);
  uint4 tr = *(const uint4*)&tb[(size_t)row * 512 + cbase];
  float tv[8];
  {
    const unsigned* u = (const unsigned*)&tr;
#pragma unroll
    for (int w = 0; w < 4; w++) {
      tv[2 * w] = __builtin_bit_cast(float, u[w] << 16);
      tv[2 * w + 1] = __builtin_bit_cast(float, u[w] & 0xFFFF0000u);
    }
  }
  ushort outv[8];
#pragma unroll
  for (int i = 0; i < 8; i++) {
    float val = (x[i] - mu) * rstd * lgam[cbase + i] + lbet[cbase + i];
    outv[i] = f2bf(tv[i] + fmaxf(val, 0.f));
  }
  *(uint4*)&hb[(size_t)row * 512 + cbase] = *(uint4*)outv;
}

// ---------------- flash attention, operand-swapped, fully unrolled+prefetch -
// grid (64 bh, 16 qt). S^T = K*Q^T: C-layout (g=quad*4+r, q=col) == B-layout
// of mfma_16x16x16bf16_1k, so exp'd P feeds PV straight from registers.
// Full 8-iter unroll; K/V/mask for iteration i+1 load while i computes
// (ILP latency hiding; occupancy is ~2 blocks/CU at this register count).
__global__ __launch_bounds__(256) void attn_kernel(
    const ushort* __restrict__ QtT, const ushort* __restrict__ KtT,
    const ushort* __restrict__ VtT, const unsigned long long* __restrict__ minv,
    ushort* __restrict__ Op) {
  int bh = blockIdx.x, qt0 = blockIdx.y;
  int b = bh >> 3, h = bh & 7;
  __shared__ float R[64 * 68];
  int tid = threadIdx.x, w = tid >> 6, lane = tid & 63;
  int quad = lane >> 4, col = lane & 15;
  int q0 = qt0 * 64;
  const ushort* Kt = KtT + (size_t)bh * 65536 + col * 32 + quad * 8;
  const ushort* Vt = VtT + (size_t)bh * 65536 + col * 16 + quad * 4;
  const ushort* Qt = QtT + (size_t)bh * 65536 + col * 32 + quad * 8;
  bhalf8 bq[4][2];
#pragma unroll
  for (int qt = 0; qt < 4; qt++)
#pragma unroll
    for (int ks = 0; ks < 2; ks++)
      bq[qt][ks] = *(const bhalf8*)(Qt + (size_t)(qt0 * 4 + qt) * 1024 + ks * 512);
  f32x4 o[4][4] = {};  // [vt][qt], O^T C-layout: v=vt*16+quad*4+r, q=qt*16+col
  float lsum[4] = {0.f, 0.f, 0.f, 0.f};
  const unsigned long long* mb = minv + (size_t)b * 16384 + q0 + col;
  const int sb = (w & 1) * 32 + quad * 4;  // wave-invariant mask shift
  const int gwoff = (w >> 1);

  bhalf8 kf[2][2][2];
  bhalf4 vf[2][2][4];
  unsigned long long mwq[2][4];
  {  // stage iteration 0
    int gs = w * 32;
#pragma unroll
    for (int qt = 0; qt < 4; qt++) mwq[0][qt] = mb[gwoff * 1024 + qt * 16];
#pragma unroll
    for (int gt = 0; gt < 2; gt++) {
      size_t gblk = (size_t)((gs >> 4) + gt) * 1024;
      kf[0][gt][0] = *(const bhalf8*)(Kt + gblk);
      kf[0][gt][1] = *(const bhalf8*)(Kt + gblk + 512);
#pragma unroll
      for (int vt = 0; vt < 4; vt++)
        vf[0][gt][vt] = *(const bhalf4*)(Vt + gblk + vt * 256);
    }
  }
#pragma unroll
  for (int it = 0; it < 8; it++) {
    const int par = it & 1;
    if (it < 7) {  // prefetch iteration it+1 into the other parity buffers
      int gsn = (it + 1) * 128 + w * 32;
      int gwn = ((it + 1) * 2) + gwoff;
#pragma unroll
      for (int qt = 0; qt < 4; qt++) mwq[par ^ 1][qt] = mb[gwn * 1024 + qt * 16];
#pragma unroll
      for (int gt = 0; gt < 2; gt++) {
        size_t gblk = (size_t)((gsn >> 4) + gt) * 1024;
        kf[par ^ 1][gt][0] = *(const bhalf8*)(Kt + gblk);
        kf[par ^ 1][gt][1] = *(const bhalf8*)(Kt + gblk + 512);
#pragma unroll
        for (int vt = 0; vt < 4; vt++)
          vf[par ^ 1][gt][vt] = *(const bhalf4*)(Vt + gblk + vt * 256);
      }
    }
#pragma unroll
    for (int gt = 0; gt < 2; gt++) {
#pragma unroll
      for (int qt = 0; qt < 4; qt++) {
        f32x4 s = {};
        s = __builtin_amdgcn_mfma_f32_16x16x32_bf16(kf[par][gt][0], bq[qt][0], s, 0, 0, 0);
        s = __builtin_amdgcn_mfma_f32_16x16x32_bf16(kf[par][gt][1], bq[qt][1], s, 0, 0, 0);
        unsigned sh = (unsigned)(mwq[par][qt] >> sb);
        unsigned pr[4];
#pragma unroll
        for (int r = 0; r < 4; r++) {
          const int pos = gt * 16 + r;  // compile-time
          unsigned keep = (unsigned)((int)(sh << (31 - pos)) >> 31);
          unsigned pu = __builtin_bit_cast(unsigned, __builtin_amdgcn_exp2f(s[r])) & keep;
          lsum[qt] += __builtin_bit_cast(float, pu);
          pr[r] = pu + 0x8000u;  // round-half-up for bf16 pack
        }
        uint2 pp;
        pp.x = __builtin_amdgcn_perm(pr[1], pr[0], 0x07060302u);
        pp.y = __builtin_amdgcn_perm(pr[3], pr[2], 0x07060302u);
        bhalf4 bp = __builtin_bit_cast(bhalf4, pp);
#pragma unroll
        for (int vt = 0; vt < 4; vt++)
          o[vt][qt] = __builtin_amdgcn_mfma_f32_16x16x16bf16_1k(vf[par][gt][vt], bp, o[vt][qt], 0, 0, 0);
      }
    }
  }
  // cross-wave reduce (partial O over g-slabs) + lsum
  for (int src = 1; src < 4; src++) {
    __syncthreads();
    if (w == src) {
      float* dst = R + lane * 68;
#pragma unroll
      for (int vt = 0; vt < 4; vt++)
#pragma unroll
        for (int qt = 0; qt < 4; qt++)
          *(f32x4*)(dst + (vt * 4 + qt) * 4) = o[vt][qt];
#pragma unroll
      for (int qt = 0; qt < 4; qt++) dst[64 + qt] = lsum[qt];
    }
    __syncthreads();
    if (w == 0) {
      const float* sp = R + lane * 68;
#pragma unroll
      for (int vt = 0; vt < 4; vt++)
#pragma unroll
        for (int qt = 0; qt < 4; qt++)
          o[vt][qt] += *(const f32x4*)(sp + (vt * 4 + qt) * 4);
#pragma unroll
      for (int qt = 0; qt < 4; qt++) lsum[qt] += sp[64 + qt];
    }
  }
  if (w == 0) {
    float rl[4];
#pragma unroll
    for (int qt = 0; qt < 4; qt++) {
      lsum[qt] += __shfl_xor(lsum[qt], 16, 64);
      lsum[qt] += __shfl_xor(lsum[qt], 32, 64);
      rl[qt] = __builtin_amdgcn_rcpf(lsum[qt]);
    }
#pragma unroll
    for (int vt = 0; vt < 4; vt++)
#pragma unroll
      for (int qt = 0; qt < 4; qt++) {
        ushort4 pk;
        pk.x = f2bf(o[vt][qt][0] * rl[qt]);
        pk.y = f2bf(o[vt][qt][1] * rl[qt]);
        pk.z = f2bf(o[vt][qt][2] * rl[qt]);
        pk.w = f2bf(o[vt][qt][3] * rl[qt]);
        *(ushort4*)&Op[(size_t)(b * 1024 + q0 + qt * 16 + col) * 512 +
                       h * 64 + vt * 16 + quad * 4] = pk;
      }
  }
}

extern "C" void kernel_launch(void* const* d_in, const int* in_sizes, int n_in,
                              void* d_out, int out_size, void* d_ws, size_t ws_size,
                              hipStream_t stream) {
  const float* q    = (const float*)d_in[0];
  const int*   mask = (const int*)d_in[1];
  const float* eps1 = (const float*)d_in[2];
  const float* U_w  = (const float*)d_in[3];
  const float* U_b  = (const float*)d_in[4];
  const float* V_w  = (const float*)d_in[5];
  const float* V_b  = (const float*)d_in[6];
  const float* ln_g = (const float*)d_in[7];
  const float* ln_b = (const float*)d_in[8];
  const float* Wq   = (const float*)d_in[9];
  const float* Wk   = (const float*)d_in[10];
  const float* Wv   = (const float*)d_in[11];
  const float* Wo   = (const float*)d_in[12];
  float* out = (float*)d_out;

  char* ws = (char*)d_ws;
  auto carve = [&](size_t bytes) { char* p = ws; ws += bytes; return p; };
  ushort* qb   = (ushort*)carve(8388608);
  ushort* uwb  = (ushort*)carve(1572864);
  ushort* vwb  = (ushort*)carve(1572864);
  ushort* e1b  = (ushort*)carve(524288);
  ushort* e1t  = (ushort*)carve(524288);
  ushort* wqkv = (ushort*)carve(1572864);
  ushort* wot  = (ushort*)carve(524288);
  ushort* A1b  = (ushort*)carve(1572864);  // A1_l = eps1 @ Uw_l.T
  ushort* Gtb  = (ushort*)carve(1572864);  // Gt_l[n][d]
  float*  cvec = (float*)carve(6144);
  unsigned long long* minv = (unsigned long long*)carve(1048576);
  ushort* tb   = (ushort*)carve(8388608);
  float*  zf   = (float*)carve(16777216);
  ushort* hb   = (ushort*)carve(8388608);
  ushort* Qtt  = (ushort*)carve(8388608);
  ushort* Ktt  = (ushort*)carve(8388608);
  ushort* Vtt  = (ushort*)carve(8388608);
  ushort* Ob   = (ushort*)carve(8388608);
  const int BIG = 1 << 30;

  prep_kernel<<<61824, 256, 0, stream>>>(q, mask, eps1, U_w, V_w, Wq, Wk, Wv, Wo,
                                         U_b, V_b, qb, minv, uwb, vwb, e1b, e1t,
                                         wqkv, wot, cvec);
  // A1[d, l*512+j] = sum_k eps1[d,k] Uw_l[j,k]
  gemm_nt<128><<<dim3(4, 12), 256, 0, stream>>>(
      e1b, nullptr, uwb, nullptr, BIG, 0, 512, 512,
      A1b, nullptr, 0, A1b + 262144, nullptr, 0, A1b + 524288, nullptr, 0);
  // Gt[l*512+n, d] = sum_j Vw_l[n,j] A1_l[d,j]
  gemm_nt<64><<<dim3(12, 8), 256, 0, stream>>>(
      vwb, nullptr, A1b, nullptr, BIG, 262144, 1536, 512,
      Gtb, nullptr, 0, nullptr, nullptr, 0, nullptr, nullptr, 0);
  const ushort* hsrc = qb;
  for (int l = 0; l < 3; l++) {
    // region0 -> t = h@eps1 (bf16), region1 -> z = h@G_l + c_l (fp32)
    gemm_nt<64><<<dim3(64, 16), 256, 0, stream>>>(
        hsrc, nullptr, e1t, Gtb + l * 262144, 512, 0, 8192, 512,
        tb, nullptr, 0, (ushort*)zf, cvec + l * 512, 1, nullptr, nullptr, 0);
    ln_kernel<<<2048, 256, 0, stream>>>(zf, tb, ln_g + l * 512, ln_b + l * 512, hb);
    hsrc = hb;
  }
  // fused QKV: region0=Q tiled (A=qb), region1=K tiled, region2=V^T tiled (A=hb)
  gemm_nt<64><<<dim3(64, 24), 256, 0, stream>>>(
      qb, hb, wqkv, nullptr, BIG, 0, 8192, 512,
      Qtt, nullptr, 2, Ktt, nullptr, 2, Vtt, nullptr, 3);
  attn_kernel<<<dim3(64, 16), 256, 0, stream>>>(Qtt, Ktt, Vtt, minv, Ob);
  gemm_nt<64><<<dim3(64, 8), 256, 0, stream>>>(
      Ob, nullptr, wot, nullptr, BIG, 0, 8192, 512,
      (ushort*)out, nullptr, 1, nullptr, nullptr, 0, nullptr, nullptr, 0);
}